// Round 1
// baseline (1444.645 us; speedup 1.0000x reference)
//
#include <hip/hip_runtime.h>

// ---------------------------------------------------------------------------
// Decoder: h0/c0 init GEMMs -> 32 sequential LSTM steps -> one big FC GEMM.
// All matmuls in bf16 MFMA (16x16x32, fp32 accum). Cell math fp32.
// Sizes: B=64 T=32 E=512 H=1024 V=10000 F=2048.
// ---------------------------------------------------------------------------

#define B_  64
#define T_  32
#define E_  512
#define H_  1024
#define V_  10000
#define F_  2048

typedef short short8 __attribute__((ext_vector_type(8)));
typedef float floatx4 __attribute__((ext_vector_type(4)));

__device__ __forceinline__ float bf2f(unsigned short u) {
  union { unsigned int i; float f; } c; c.i = ((unsigned int)u) << 16; return c.f;
}
__device__ __forceinline__ unsigned short f2bf(float f) {
  union { float f; unsigned int i; } c; c.f = f;
  unsigned int x = c.i;
  return (unsigned short)((x + 0x7fffu + ((x >> 16) & 1u)) >> 16);
}
__device__ __forceinline__ float sigmoidf_(float x) {
  return 1.0f / (1.0f + __expf(-x));
}

// ---------------- fp32 -> bf16 bulk convert (vectorized, grid-stride) ------
__global__ __launch_bounds__(256) void cvt_f32_bf16(
    const float* __restrict__ src, unsigned short* __restrict__ dst, int n4) {
  int i = blockIdx.x * blockDim.x + threadIdx.x;
  int stride = gridDim.x * blockDim.x;
  for (; i < n4; i += stride) {
    float4 v = ((const float4*)src)[i];
    ushort4 o;
    o.x = f2bf(v.x); o.y = f2bf(v.y); o.z = f2bf(v.z); o.w = f2bf(v.w);
    ((ushort4*)dst)[i] = o;
  }
}

// ---------------- embedding gather -> bf16, rows ordered (t*64+b) ----------
__global__ __launch_bounds__(128) void embed_gather(
    const float* __restrict__ table, const int* __restrict__ captions,
    unsigned short* __restrict__ out) {
  int row = blockIdx.x;            // row = t*B + b
  int t = row >> 6, b = row & 63;
  int idx = captions[b * T_ + t];
  const float4* src = (const float4*)(table + (size_t)idx * E_);
  ushort4* dst = (ushort4*)(out + (size_t)row * E_);
  for (int e = threadIdx.x; e < E_ / 4; e += blockDim.x) {
    float4 v = src[e];
    ushort4 o;
    o.x = f2bf(v.x); o.y = f2bf(v.y); o.z = f2bf(v.z); o.w = f2bf(v.w);
    dst[e] = o;
  }
}

// ---------------- generic bf16 MFMA GEMM: C = act(A @ W^T + b1 + b2) -------
// A: [M,K] bf16 row-major.  W: [N,K] bf16 row-major.  M % 64 == 0, K % 32 == 0.
// Block = 256 thr = 4 waves; block tile 64(M) x 64(N); wave tile 64(M) x 16(N).
template <int ACT_SIGMOID, int OUT_BF16>
__global__ __launch_bounds__(256) void mfma_gemm(
    const unsigned short* __restrict__ A, const unsigned short* __restrict__ W,
    const float* __restrict__ bias1, const float* __restrict__ bias2,
    void* __restrict__ out, int M, int N, int K) {
  const int lane = threadIdx.x & 63;
  const int wave = threadIdx.x >> 6;
  const int m_base = blockIdx.x * 64;
  const int l15 = lane & 15;
  const int kb = (lane >> 4) * 8;               // k-offset of this lane's quad
  const int n = blockIdx.y * 64 + wave * 16 + l15;
  const int nr = (n < N) ? n : (N - 1);         // clamp for ragged N tail

  const unsigned short* Wp = W + (size_t)nr * K + kb;
  const unsigned short* Ap = A + (size_t)(m_base + l15) * K + kb;

  floatx4 acc[4];
#pragma unroll
  for (int i = 0; i < 4; ++i) acc[i] = (floatx4){0.f, 0.f, 0.f, 0.f};

  for (int k0 = 0; k0 < K; k0 += 32) {
    short8 bf = *(const short8*)(Wp + k0);
#pragma unroll
    for (int mt = 0; mt < 4; ++mt) {
      short8 af = *(const short8*)(Ap + (size_t)mt * 16 * K + k0);
      acc[mt] = __builtin_amdgcn_mfma_f32_16x16x32_bf16(af, bf, acc[mt], 0, 0, 0);
    }
  }

  if (n < N) {
    float bsum = (bias1 ? bias1[n] : 0.f) + (bias2 ? bias2[n] : 0.f);
#pragma unroll
    for (int mt = 0; mt < 4; ++mt) {
#pragma unroll
      for (int r = 0; r < 4; ++r) {
        int m = m_base + mt * 16 + (lane >> 4) * 4 + r;
        float v = acc[mt][r] + bsum;
        if (ACT_SIGMOID) v = sigmoidf_(v);
        if (OUT_BF16)
          ((unsigned short*)out)[(size_t)m * N + n] = f2bf(v);
        else
          ((float*)out)[(size_t)m * N + n] = v;
      }
    }
  }
}

// ---------------- fused recurrent step: gates = gx + h@W_hh^T; cell --------
// Grid: 64 blocks (16 H-cols each). Block = 4 waves; wave g computes gate g
// for its 16 cols x all 64 batches via 4 MFMA m-tiles. Cell math via LDS.
__global__ __launch_bounds__(256) void lstm_step(
    const unsigned short* __restrict__ h_prev,  // [B,H] bf16
    const unsigned short* __restrict__ W_hh,    // [4H,H] bf16
    const unsigned short* __restrict__ gx_t,    // [B,4H] bf16 (x-part + biases)
    float* __restrict__ c,                      // [B,H] f32, in-place
    unsigned short* __restrict__ h_out) {       // [B,H] bf16
  const int lane = threadIdx.x & 63;
  const int g = threadIdx.x >> 6;               // gate index: i,f,g,o
  const int n0 = blockIdx.x * 16;
  const int l15 = lane & 15;
  const int kb = (lane >> 4) * 8;

  const unsigned short* Wp = W_hh + (size_t)(g * H_ + n0 + l15) * H_ + kb;
  const unsigned short* Ap = h_prev + (size_t)l15 * H_ + kb;

  floatx4 acc[4];
#pragma unroll
  for (int i = 0; i < 4; ++i) acc[i] = (floatx4){0.f, 0.f, 0.f, 0.f};

  for (int k0 = 0; k0 < H_; k0 += 32) {
    short8 bf = *(const short8*)(Wp + k0);
#pragma unroll
    for (int mt = 0; mt < 4; ++mt) {
      short8 af = *(const short8*)(Ap + (size_t)mt * 16 * H_ + k0);
      acc[mt] = __builtin_amdgcn_mfma_f32_16x16x32_bf16(af, bf, acc[mt], 0, 0, 0);
    }
  }

  __shared__ float gbuf[4][B_][16];
#pragma unroll
  for (int mt = 0; mt < 4; ++mt)
#pragma unroll
    for (int r = 0; r < 4; ++r)
      gbuf[g][mt * 16 + (lane >> 4) * 4 + r][l15] = acc[mt][r];
  __syncthreads();

#pragma unroll
  for (int i = 0; i < 4; ++i) {
    int p = threadIdx.x + i * 256;   // 1024 (b, j) pairs
    int b = p >> 4, j = p & 15;
    int col = n0 + j;
    float xi = gbuf[0][b][j] + bf2f(gx_t[b * (4 * H_) + 0 * H_ + col]);
    float xf = gbuf[1][b][j] + bf2f(gx_t[b * (4 * H_) + 1 * H_ + col]);
    float xg = gbuf[2][b][j] + bf2f(gx_t[b * (4 * H_) + 2 * H_ + col]);
    float xo = gbuf[3][b][j] + bf2f(gx_t[b * (4 * H_) + 3 * H_ + col]);
    xi = sigmoidf_(xi);
    xf = sigmoidf_(xf);
    xg = tanhf(xg);
    xo = sigmoidf_(xo);
    int ci = b * H_ + col;
    float cn = xf * c[ci] + xi * xg;
    c[ci] = cn;
    h_out[ci] = f2bf(xo * tanhf(cn));
  }
}

// ---------------------------------------------------------------------------
extern "C" void kernel_launch(void* const* d_in, const int* in_sizes, int n_in,
                              void* d_out, int out_size, void* d_ws, size_t ws_size,
                              hipStream_t stream) {
  const float* features    = (const float*)d_in[0];
  const int*   captions    = (const int*)d_in[1];
  const float* embed_table = (const float*)d_in[2];
  const float* W_init_h    = (const float*)d_in[3];
  const float* b_init_h    = (const float*)d_in[4];
  const float* W_init_c    = (const float*)d_in[5];
  const float* b_init_c    = (const float*)d_in[6];
  const float* W_ih        = (const float*)d_in[7];
  const float* b_ih        = (const float*)d_in[8];
  const float* W_hh        = (const float*)d_in[9];
  const float* b_hh        = (const float*)d_in[10];
  const float* W_fc        = (const float*)d_in[11];
  const float* b_fc        = (const float*)d_in[12];
  float* out = (float*)d_out;

  // ---- workspace carve-up (bump allocator, 256B aligned) ----
  char* ws = (char*)d_ws;
  auto alloc = [&](size_t bytes) -> char* {
    char* p = ws;
    ws += (bytes + 255) & ~(size_t)255;
    return p;
  };
  unsigned short* W_ih_b  = (unsigned short*)alloc((size_t)4 * H_ * E_ * 2);
  unsigned short* W_hh_b  = (unsigned short*)alloc((size_t)4 * H_ * H_ * 2);
  unsigned short* W_fc_b  = (unsigned short*)alloc((size_t)V_ * H_ * 2);
  unsigned short* Wih0_b  = (unsigned short*)alloc((size_t)H_ * F_ * 2);
  unsigned short* Wic0_b  = (unsigned short*)alloc((size_t)H_ * F_ * 2);
  unsigned short* feat_b  = (unsigned short*)alloc((size_t)B_ * F_ * 2);
  unsigned short* emb_b   = (unsigned short*)alloc((size_t)T_ * B_ * E_ * 2);
  unsigned short* gx_b    = (unsigned short*)alloc((size_t)T_ * B_ * 4 * H_ * 2);
  unsigned short* h_all   = (unsigned short*)alloc((size_t)(T_ + 1) * B_ * H_ * 2);
  float*          c_f32   = (float*)alloc((size_t)B_ * H_ * 4);
  (void)ws_size; (void)in_sizes; (void)n_in; (void)out_size;

  // ---- weight / input conversions to bf16 ----
  auto cvt = [&](const float* s, unsigned short* d, size_t n) {
    int n4 = (int)(n / 4);
    int blocks = (n4 + 255) / 256;
    if (blocks > 2048) blocks = 2048;
    hipLaunchKernelGGL(cvt_f32_bf16, dim3(blocks), dim3(256), 0, stream, s, d, n4);
  };
  cvt(W_ih, W_ih_b, (size_t)4 * H_ * E_);
  cvt(W_hh, W_hh_b, (size_t)4 * H_ * H_);
  cvt(W_fc, W_fc_b, (size_t)V_ * H_);
  cvt(W_init_h, Wih0_b, (size_t)H_ * F_);
  cvt(W_init_c, Wic0_b, (size_t)H_ * F_);
  cvt(features, feat_b, (size_t)B_ * F_);

  hipLaunchKernelGGL(embed_gather, dim3(T_ * B_), dim3(128), 0, stream,
                     embed_table, captions, emb_b);

  // ---- h0 (bf16 into h_all slot 0) and c0 (fp32) ----
  hipLaunchKernelGGL((mfma_gemm<0, 1>), dim3(1, H_ / 64), dim3(256), 0, stream,
                     feat_b, Wih0_b, b_init_h, (const float*)nullptr,
                     (void*)h_all, B_, H_, F_);
  hipLaunchKernelGGL((mfma_gemm<0, 0>), dim3(1, H_ / 64), dim3(256), 0, stream,
                     feat_b, Wic0_b, b_init_c, (const float*)nullptr,
                     (void*)c_f32, B_, H_, F_);

  // ---- precompute all x-side gate contributions: gx = emb @ W_ih^T + b_ih + b_hh
  hipLaunchKernelGGL((mfma_gemm<0, 1>), dim3(T_ * B_ / 64, 4 * H_ / 64), dim3(256), 0, stream,
                     emb_b, W_ih_b, b_ih, b_hh, (void*)gx_b,
                     T_ * B_, 4 * H_, E_);

  // ---- 32 sequential recurrent steps ----
  for (int t = 0; t < T_; ++t) {
    hipLaunchKernelGGL(lstm_step, dim3(H_ / 16), dim3(256), 0, stream,
                       h_all + (size_t)t * B_ * H_,
                       W_hh_b,
                       gx_b + (size_t)t * B_ * 4 * H_,
                       c_f32,
                       h_all + (size_t)(t + 1) * B_ * H_);
  }

  // ---- final FC: out[t*B+b, v] = sigmoid(h_all[1..32] @ W_fc^T + b_fc) ----
  hipLaunchKernelGGL((mfma_gemm<1, 0>), dim3(T_ * B_ / 64, (V_ + 63) / 64), dim3(256), 0, stream,
                     h_all + (size_t)B_ * H_, W_fc_b, b_fc, (const float*)nullptr,
                     (void*)out, T_ * B_, V_, H_);
}